// Round 1
// baseline (113.536 us; speedup 1.0000x reference)
//
#include <hip/hip_runtime.h>

typedef __attribute__((ext_vector_type(4))) float  f32x4;
typedef __attribute__((ext_vector_type(8))) short  bf16x8;
typedef __attribute__((ext_vector_type(4))) short  bf16x4;
typedef __attribute__((ext_vector_type(4))) unsigned int u32x4;
typedef __attribute__((ext_vector_type(2))) unsigned int u32x2;

#define MFMA16(a,b,c) __builtin_amdgcn_mfma_f32_16x16x32_bf16(a,b,c,0,0,0)
#define LOG2E 1.44269504f
#define PBIAS 17.3123405f   /* 12*log2(e): p = exp2(s*0.25*LOG2E - PBIAS); normalized by sum -> exact */

static __device__ __forceinline__ unsigned short f2bf(float f){
  unsigned int u = __float_as_uint(f);
  u += 0x7fffu + ((u>>16)&1u);
  return (unsigned short)(u>>16);
}
static __device__ __forceinline__ float bf2f(unsigned short h){
  return __uint_as_float(((unsigned int)h)<<16);
}
static __device__ __forceinline__ unsigned int pk2(float a, float b){
  return (unsigned)f2bf(a) | (((unsigned)f2bf(b))<<16);
}

// ---------------------------------------------------------------------------
// prep: q,k = x @ w^T + b  (bf16 out), and xbT[b][d][s] = bf16(x) transposed
// grid 256 blocks x 256 thr; each block = 64 rows of flat [8*2048]
// ---------------------------------------------------------------------------
__global__ __launch_bounds__(256,2) void prep_kernel(
    const float* __restrict__ x,  const float* __restrict__ wq, const float* __restrict__ bq,
    const float* __restrict__ wk, const float* __restrict__ bk,
    unsigned short* __restrict__ qws, unsigned short* __restrict__ kws,
    unsigned short* __restrict__ xbT)
{
  __shared__ __align__(16) unsigned short wlds[32*1032];  // [32 e][1024 k] pad 8
  __shared__ __align__(16) unsigned short xlds[64*72];    // [64 s][64 k] pad 8
  const int t  = threadIdx.x;
  const int r0 = blockIdx.x<<6;
  const int b  = r0>>11;
  const int s0 = r0&2047;
  const int l = t&63, w = t>>6, g = l>>4, li = l&15;

  // stage weights once (rows 0..15 = wq, 16..31 = wk)
  {
    const int n = t>>3, part = t&7;
    const float* wsrc = (n<16) ? (wq + n*1024) : (wk + (n-16)*1024);
    #pragma unroll
    for(int cc=0; cc<16; ++cc){
      const int d = part*128 + cc*8;
      f32x4 f0 = *(const f32x4*)(wsrc + d);
      f32x4 f1 = *(const f32x4*)(wsrc + d + 4);
      u32x4 p;
      p[0]=pk2(f0[0],f0[1]); p[1]=pk2(f0[2],f0[3]);
      p[2]=pk2(f1[0],f1[1]); p[3]=pk2(f1[2],f1[3]);
      *(u32x4*)(&wlds[n*1032 + d]) = p;
    }
  }
  __syncthreads();

  f32x4 acc0 = {0.f,0.f,0.f,0.f};
  f32x4 acc1 = {0.f,0.f,0.f,0.f};
  const int srow = t>>2, dch = t&3;   // staging roles
  const int dd = t&63, sch = t>>6;    // transpose roles

  for(int it=0; it<16; ++it){
    { // stage x[64][64] -> bf16 LDS (coalesced f32x4 reads)
      const float* xp = x + (size_t)(r0+srow)*1024 + it*64 + dch*16;
      f32x4 a0 = *(const f32x4*)(xp);
      f32x4 a1 = *(const f32x4*)(xp+4);
      f32x4 a2 = *(const f32x4*)(xp+8);
      f32x4 a3 = *(const f32x4*)(xp+12);
      u32x4 p0, p1;
      p0[0]=pk2(a0[0],a0[1]); p0[1]=pk2(a0[2],a0[3]);
      p0[2]=pk2(a1[0],a1[1]); p0[3]=pk2(a1[2],a1[3]);
      p1[0]=pk2(a2[0],a2[1]); p1[1]=pk2(a2[2],a2[3]);
      p1[2]=pk2(a3[0],a3[1]); p1[3]=pk2(a3[2],a3[3]);
      *(u32x4*)(&xlds[srow*72 + dch*16])     = p0;
      *(u32x4*)(&xlds[srow*72 + dch*16 + 8]) = p1;
    }
    __syncthreads();
    // MFMA: C[s][e] += x[s][k]*w[e][k]
    #pragma unroll
    for(int ks=0; ks<2; ++ks){
      bf16x8 a  = *(const bf16x8*)(&xlds[(16*w+li)*72       + ks*32 + g*8]);
      bf16x8 b0 = *(const bf16x8*)(&wlds[ li*1032     + it*64 + ks*32 + g*8]);
      bf16x8 b1 = *(const bf16x8*)(&wlds[(16+li)*1032 + it*64 + ks*32 + g*8]);
      acc0 = MFMA16(a,b0,acc0);
      acc1 = MFMA16(a,b1,acc1);
    }
    { // transpose-write xbT[b][d][s]: thread owns column dd, s-range sch*16..+15
      unsigned short v[16];
      #pragma unroll
      for(int jj=0; jj<16; ++jj) v[jj] = xlds[(sch*16 + jj)*72 + dd];
      u32x4 o0, o1;
      o0[0]=(unsigned)v[0]|((unsigned)v[1]<<16);   o0[1]=(unsigned)v[2]|((unsigned)v[3]<<16);
      o0[2]=(unsigned)v[4]|((unsigned)v[5]<<16);   o0[3]=(unsigned)v[6]|((unsigned)v[7]<<16);
      o1[0]=(unsigned)v[8]|((unsigned)v[9]<<16);   o1[1]=(unsigned)v[10]|((unsigned)v[11]<<16);
      o1[2]=(unsigned)v[12]|((unsigned)v[13]<<16); o1[3]=(unsigned)v[14]|((unsigned)v[15]<<16);
      unsigned short* dst = xbT + (size_t)(b*1024 + it*64 + dd)*2048 + s0 + sch*16;
      *(u32x4*)(dst)   = o0;
      *(u32x4*)(dst+8) = o1;
    }
    __syncthreads();
  }
  // epilogue: bias + store bf16 q,k. C: col=li(e), row=16w+4g+reg
  #pragma unroll
  for(int reg=0; reg<4; ++reg){
    const int sr = r0 + 16*w + 4*g + reg;
    qws[(size_t)sr*16 + li] = f2bf(acc0[reg] + bq[li]);
    kws[(size_t)sr*16 + li] = f2bf(acc1[reg] + bk[li]);
  }
}

// ---------------------------------------------------------------------------
// attn: per block = (b, 64-q block, 512-d half). Flash w/ fixed exp-bias,
// epilogue normalization by accumulated p-sums.
// grid 512 x 512 thr (8 waves). LDS: xT tile dbuf [512][40bf16] + P [64][48bf16]
// ---------------------------------------------------------------------------
__global__ __launch_bounds__(512,2) void attn_kernel(
    const unsigned short* __restrict__ qws, const unsigned short* __restrict__ kws,
    const unsigned short* __restrict__ xbT, float* __restrict__ out)
{
  __shared__ __align__(16) unsigned char smem[2*40960 + 64*96];
  __shared__ float psA[2][64];
  const int t = threadIdx.x;
  const int l = t&63, w = t>>6, g = l>>4, li = l&15;
  const int rf = w>>2, cf = w&3;          // S role: S^T frag (rf: kv-half, cf: q-quarter)
  const int bi = blockIdx.x;
  const int b = bi&7;                      // XCD batch affinity (idx%8)
  const int j = bi>>3;
  int qb, dh;
  if(j < 32){ qb = 31 - (j>>1); dh = j&1; }          // LPT: big qb dispatched first
  else      { qb = 15 - ((j-32)>>1); dh = (j-32)&1; }
  const int q0 = qb<<6, d0 = dh<<9, nt = 2*qb + 2;
  const int sd = t>>2, sc = t&3;           // staging roles
  const int qrow = q0 + 16*cf + li;

  const bf16x8 zero8 = {0,0,0,0,0,0,0,0};
  bf16x8 qfrag = zero8;
  if(g < 2) qfrag = *(const bf16x8*)(qws + ((size_t)(b*2048 + qrow)<<4) + 8*g);

  f32x4 acc[4][4];
  #pragma unroll
  for(int a_=0;a_<4;++a_)
    #pragma unroll
    for(int b_=0;b_<4;++b_){ acc[a_][b_][0]=0.f; acc[a_][b_][1]=0.f; acc[a_][b_][2]=0.f; acc[a_][b_][3]=0.f; }
  float sp = 0.f;

  u32x4 sreg[4];
  bf16x8 kcur = zero8, knxt = zero8;

  // prologue: stage tile 0 into buf 0
  #pragma unroll
  for(int v=0; v<4; ++v){
    const int dloc = sd + (v<<7);
    sreg[v] = *(const u32x4*)(xbT + (size_t)(b*1024 + d0 + dloc)*2048 + sc*8);
  }
  if(g < 2) kcur = *(const bf16x8*)(kws + ((size_t)(b*2048 + 16*rf + li)<<4) + 8*g);
  #pragma unroll
  for(int v=0; v<4; ++v){
    const int dloc = sd + (v<<7);
    *(u32x4*)(&smem[dloc*80 + sc*16]) = sreg[v];
  }
  __syncthreads();

  for(int tt=0; tt<nt; ++tt){
    const bool pf = (tt+1 < nt);
    if(pf){ // issue next-tile global loads early (latency hides under S + PV)
      const int kv0n = (tt+1)<<5;
      #pragma unroll
      for(int v=0; v<4; ++v){
        const int dloc = sd + (v<<7);
        sreg[v] = *(const u32x4*)(xbT + (size_t)(b*1024 + d0 + dloc)*2048 + kv0n + sc*8);
      }
      knxt = zero8;
      if(g < 2) knxt = *(const bf16x8*)(kws + ((size_t)(b*2048 + kv0n + 16*rf + li)<<4) + 8*g);
    }
    { // ---- S phase: S^T frag = mfma(K, Q); p = exp2(s/4*log2e - C); write P in slot order
      f32x4 z = {0.f,0.f,0.f,0.f};
      f32x4 s4 = MFMA16(kcur, qfrag, z);
      const int kvb = (tt<<5) + 16*rf + 4*g;
      float p0 = (kvb+0 <= qrow) ? exp2f(fmaf(s4[0], 0.25f*LOG2E, -PBIAS)) : 0.f;
      float p1 = (kvb+1 <= qrow) ? exp2f(fmaf(s4[1], 0.25f*LOG2E, -PBIAS)) : 0.f;
      float p2 = (kvb+2 <= qrow) ? exp2f(fmaf(s4[2], 0.25f*LOG2E, -PBIAS)) : 0.f;
      float p3 = (kvb+3 <= qrow) ? exp2f(fmaf(s4[3], 0.25f*LOG2E, -PBIAS)) : 0.f;
      const unsigned short h0=f2bf(p0), h1=f2bf(p1), h2=f2bf(p2), h3=f2bf(p3);
      sp += bf2f(h0)+bf2f(h1)+bf2f(h2)+bf2f(h3);   // sum of the bf16-rounded values actually used
      u32x2 ph; ph[0]=(unsigned)h0|((unsigned)h1<<16); ph[1]=(unsigned)h2|((unsigned)h3<<16);
      *(u32x2*)(&smem[81920 + (16*cf+li)*96 + 16*g + 8*rf]) = ph;
    }
    __syncthreads();
    { // ---- PV phase: out[64q x 64d slice] += P @ X
      const unsigned char* xbuf = &smem[(tt&1)*40960];
      bf16x8 a0 = *(const bf16x8*)(&smem[81920 + (     li)*96 + 16*g]);
      bf16x8 a1 = *(const bf16x8*)(&smem[81920 + (16 + li)*96 + 16*g]);
      bf16x8 a2 = *(const bf16x8*)(&smem[81920 + (32 + li)*96 + 16*g]);
      bf16x8 a3 = *(const bf16x8*)(&smem[81920 + (48 + li)*96 + 16*g]);
      #pragma unroll
      for(int cfp=0; cfp<4; ++cfp){
        const int dloc = (w<<6) + (cfp<<4) + li;
        bf16x4 blo = *(const bf16x4*)(xbuf + dloc*80 + 8*g);       // kv 4g..4g+3
        bf16x4 bhi = *(const bf16x4*)(xbuf + dloc*80 + 32 + 8*g);  // kv 16+4g..+3
        bf16x8 bf_ = __builtin_shufflevector(blo, bhi, 0,1,2,3,4,5,6,7);
        acc[0][cfp] = MFMA16(a0, bf_, acc[0][cfp]);
        acc[1][cfp] = MFMA16(a1, bf_, acc[1][cfp]);
        acc[2][cfp] = MFMA16(a2, bf_, acc[2][cfp]);
        acc[3][cfp] = MFMA16(a3, bf_, acc[3][cfp]);
      }
    }
    if(pf){ // write prefetched tile into the other buffer
      const int bufn = (tt+1)&1;
      #pragma unroll
      for(int v=0; v<4; ++v){
        const int dloc = sd + (v<<7);
        *(u32x4*)(&smem[bufn*40960 + dloc*80 + sc*16]) = sreg[v];
      }
      kcur = knxt;
    }
    __syncthreads();
  }

  // p-sum reduce across the 4 lane-groups sharing a q column, then across rf halves
  sp += __shfl_xor(sp, 16);
  sp += __shfl_xor(sp, 32);
  if(l < 16) psA[rf][16*cf + l] = sp;
  __syncthreads();

  // epilogue: normalize and store
  #pragma unroll
  for(int rfp=0; rfp<4; ++rfp){
    #pragma unroll
    for(int reg=0; reg<4; ++reg){
      const int qloc = 16*rfp + 4*g + reg;
      const float linv = 1.0f/(psA[0][qloc] + psA[1][qloc]);
      #pragma unroll
      for(int cfp=0; cfp<4; ++cfp){
        const int dpos = d0 + (w<<6) + (cfp<<4) + li;
        out[(size_t)(b*2048 + q0 + qloc)*1024 + dpos] = acc[rfp][cfp][reg]*linv;
      }
    }
  }
}

// ---------------------------------------------------------------------------
extern "C" void kernel_launch(void* const* d_in, const int* in_sizes, int n_in,
                              void* d_out, int out_size, void* d_ws, size_t ws_size,
                              hipStream_t stream) {
  (void)in_sizes; (void)n_in; (void)out_size; (void)ws_size;
  const float* x  = (const float*)d_in[0];
  const float* wq = (const float*)d_in[1];
  const float* bq = (const float*)d_in[2];
  const float* wk = (const float*)d_in[3];
  const float* bk = (const float*)d_in[4];
  float* out = (float*)d_out;
  char* ws = (char*)d_ws;
  unsigned short* qws = (unsigned short*)(ws);             // 512KB  [8*2048][16] bf16
  unsigned short* kws = (unsigned short*)(ws + (512<<10)); // 512KB
  unsigned short* xbT = (unsigned short*)(ws + (2<<20));   // 33.5MB [8][1024][2048] bf16
  hipLaunchKernelGGL(prep_kernel, dim3(256), dim3(256), 0, stream, x, wq, bq, wk, bk, qws, kws, xbT);
  hipLaunchKernelGGL(attn_kernel, dim3(512), dim3(512), 0, stream, qws, kws, xbT, out);
}